// Round 2
// baseline (359.341 us; speedup 1.0000x reference)
//
#include <hip/hip_runtime.h>

// Geometry (fixed by reference)
#define NTOK 197
#define NHEADS 12
#define DIM 768
#define PP 20          // pool size
#define KK 5           // top-k
#define STOT 397       // 197 + 200
#define BB 128
#define NIMG 196
#define NIMGTOK (BB*NIMG)   // 25088 = 98*256 exactly
#define NALLTOK (BB*NTOK)   // 25216

static const long long MASK_ELEMS = (long long)BB * NHEADS * NTOK * STOT; // 120129024

typedef float float4a __attribute__((ext_vector_type(4), aligned(4)));

// ---------------- Kernel 1: inverse norms of the 40 keys at `layer` -------------
__global__ void knorm_kernel(const float* __restrict__ kc,
                             const float* __restrict__ ki,
                             const int* __restrict__ layer_p,
                             float* __restrict__ invn /*40 floats*/) {
    int layer = *layer_p;
    int kid = blockIdx.x;              // 0..39 ; 0-19 cls, 20-39 img
    const float* base = (kid < PP ? kc : ki) + (size_t)layer * PP * DIM;
    const float* kp = base + (size_t)(kid % PP) * DIM;
    int lane = threadIdx.x;            // 64 threads
    float s = 0.f;
    for (int i = lane; i < DIM; i += 64) { float v = kp[i]; s += v * v; }
    #pragma unroll
    for (int m = 1; m < 64; m <<= 1) s += __shfl_xor(s, m, 64);
    if (lane == 0) invn[kid] = 1.0f / fmaxf(sqrtf(s), 1e-12f);
}

// ---------------- Kernel 2: routing (bits + per-token dist) ---------------------
// blocks 0..97: image tokens, ONE TOKEN PER THREAD (no cross-lane reduce).
// blocks 98..225: cls token per block (old butterfly scheme; only 128 blocks).
__global__ __launch_bounds__(256) void route_kernel(
        const float* __restrict__ x,
        const float* __restrict__ kc,
        const float* __restrict__ ki,
        const int* __restrict__ layer_p,
        const float* __restrict__ invn,
        int* __restrict__ bits_ws,     /* [25216] */
        float* __restrict__ dist_ws    /* [25216] */) {
    const int tid = threadIdx.x;
    const int layer = *layer_p;

    if (blockIdx.x < 98) {
        // ---------- per-thread image-token routing ----------
        const int i = blockIdx.x * 256 + tid;       // 0..25087
        const int b = i / NIMG;
        const int tt = i - b * NIMG;                // 0..195
        const int tok = b * NTOK + 1 + tt;
        const float* xr = x + (size_t)tok * DIM;
        const float* kb = ki + (size_t)layer * PP * DIM;   // wave-uniform
        const float* ik = invn + PP;

        float acc[PP];
        #pragma unroll
        for (int p = 0; p < PP; ++p) acc[p] = 0.f;
        float xsq = 0.f;

        for (int d0 = 0; d0 < DIM; d0 += 8) {
            float4 a = *(const float4*)(xr + d0);
            float4 c = *(const float4*)(xr + d0 + 4);
            xsq += a.x*a.x + a.y*a.y + a.z*a.z + a.w*a.w
                 + c.x*c.x + c.y*c.y + c.z*c.z + c.w*c.w;
            #pragma unroll
            for (int p = 0; p < PP; ++p) {
                const float* kp = kb + p * DIM + d0;       // uniform -> s_load
                acc[p] += a.x*kp[0] + a.y*kp[1] + a.z*kp[2] + a.w*kp[3]
                        + c.x*kp[4] + c.y*kp[5] + c.z*kp[6] + c.w*kp[7];
            }
        }

        float invx = 1.0f / fmaxf(sqrtf(xsq), 1e-12f);
        float sims[PP];
        #pragma unroll
        for (int p = 0; p < PP; ++p) sims[p] = acc[p] * invx * ik[p];

        int bits = 0; float sum5 = 0.f;
        #pragma unroll
        for (int j = 0; j < KK; ++j) {
            int bi = 0; float bv = -3.0e38f;
            #pragma unroll
            for (int p = 0; p < PP; ++p) {
                bool ok = !((bits >> p) & 1) && (sims[p] > bv);
                bv = ok ? sims[p] : bv;
                bi = ok ? p : bi;
            }
            bits |= (1 << bi);
            sum5 += bv;
        }
        bits_ws[tok] = bits;
        dist_ws[tok] = (float)KK - sum5;
    } else {
        // ---------- per-block cls-token routing (128 blocks) ----------
        const int b = blockIdx.x - 98;
        const int tok = b * NTOK;      // t == 0
        const int lane = tid & 63;
        const int wv = tid >> 6;
        const float* kb = kc + (size_t)layer * PP * DIM;
        const float* xr = x + (size_t)tok * DIM;

        float xv0 = xr[tid], xv1 = xr[tid + 256], xv2 = xr[tid + 512];
        float xsq = xv0*xv0 + xv1*xv1 + xv2*xv2;
        float acc[PP];
        #pragma unroll
        for (int p = 0; p < PP; ++p) {
            const float* kp = kb + p * DIM;
            acc[p] = xv0*kp[tid] + xv1*kp[tid+256] + xv2*kp[tid+512];
        }
        #pragma unroll
        for (int m = 1; m < 64; m <<= 1) {
            xsq += __shfl_xor(xsq, m, 64);
            #pragma unroll
            for (int p = 0; p < PP; ++p) acc[p] += __shfl_xor(acc[p], m, 64);
        }
        __shared__ float red[4][PP + 1];
        if (lane == 0) {
            #pragma unroll
            for (int p = 0; p < PP; ++p) red[wv][p] = acc[p];
            red[wv][PP] = xsq;
        }
        __syncthreads();
        if (tid == 0) {
            float xs = red[0][PP] + red[1][PP] + red[2][PP] + red[3][PP];
            float invx = 1.0f / fmaxf(sqrtf(xs), 1e-12f);
            float sims[PP];
            #pragma unroll
            for (int p = 0; p < PP; ++p)
                sims[p] = (red[0][p] + red[1][p] + red[2][p] + red[3][p]) * invx * invn[p];
            int bits = 0; float sum5 = 0.f;
            for (int j = 0; j < KK; ++j) {
                int bi = 0; float bv = -3.0e38f;
                #pragma unroll
                for (int p = 0; p < PP; ++p) {
                    bool ok = !((bits >> p) & 1) && (sims[p] > bv);
                    bv = ok ? sims[p] : bv;
                    bi = ok ? p : bi;
                }
                bits |= (1 << bi);
                sum5 += bv;
            }
            bits_ws[tok] = bits;
            dist_ws[tok] = (float)KK - sum5;
        }
    }
}

// ---------------- Kernel 3: streaming mask writer (+ dist reduce in last block) -
__global__ __launch_bounds__(256) void write_kernel(
        const int* __restrict__ bits_ws,
        const float* __restrict__ dist_ws,
        float* __restrict__ out) {
    const int bid = blockIdx.x;
    const int tid = threadIdx.x;

    if (bid == NALLTOK) {
        // dist reduction
        float sc = 0.f, si = 0.f;
        for (int tok = tid; tok < NALLTOK; tok += 256) {
            int q = tok / NTOK;
            int r = tok - q * NTOK;
            float v = dist_ws[tok];
            if (r == 0) sc += v; else si += v;
        }
        #pragma unroll
        for (int m = 1; m < 64; m <<= 1) {
            sc += __shfl_xor(sc, m, 64);
            si += __shfl_xor(si, m, 64);
        }
        __shared__ float lc[4], li[4];
        int lane = tid & 63, wv = tid >> 6;
        if (lane == 0) { lc[wv] = sc; li[wv] = si; }
        __syncthreads();
        if (tid == 0) {
            float c = lc[0] + lc[1] + lc[2] + lc[3];
            float i = li[0] + li[1] + li[2] + li[3];
            out[MASK_ELEMS] = c / (float)(BB * KK) + i / (float)(BB * NIMG * KK);
        }
        return;
    }

    const int b = bid / NTOK;
    const int t = bid - b * NTOK;
    const int bits = bits_ws[bid];

    __shared__ __align__(16) float row[STOT + 3];
    for (int s = tid; s < STOT; s += 256) {
        float v;
        if (t == 0) {
            v = (s == 0) ? 1.0f
              : (s <= 100 ? (float)((bits >> ((s - 1) / 5)) & 1)
              : (s <= 200 ? 0.0f : 1.0f));
        } else {
            v = (s == 0) ? 1.0f
              : (s <= 100 ? 0.0f
              : (s <= 200 ? (float)((bits >> ((s - 101) / 5)) & 1) : 1.0f));
        }
        row[s] = v;
    }
    __syncthreads();

    // 6 passes x 2 heads; 128 threads per head-row (99 vec4 writers + 1 tail)
    const int hl = tid >> 7;          // 0..1
    const int j  = tid & 127;         // 0..127
    const size_t hstride = (size_t)NTOK * STOT;
    float* base = out + ((size_t)(b * NHEADS) * NTOK + t) * (size_t)STOT;
    #pragma unroll
    for (int pass = 0; pass < 6; ++pass) {
        float* dst = base + (size_t)(pass * 2 + hl) * hstride;
        if (j < 99) {
            float4a v = *(const float4a*)&row[4 * j];
            __builtin_nontemporal_store(v, (float4a*)(dst + 4 * j));
        } else if (j == 99) {
            __builtin_nontemporal_store(row[396], dst + 396);
        }
    }
}

// ---------------- launcher ------------------------------------------------------
extern "C" void kernel_launch(void* const* d_in, const int* in_sizes, int n_in,
                              void* d_out, int out_size, void* d_ws, size_t ws_size,
                              hipStream_t stream) {
    const float* x  = (const float*)d_in[0];
    const float* kc = (const float*)d_in[1];
    const float* ki = (const float*)d_in[2];
    const int* layer = (const int*)d_in[3];
    float* out = (float*)d_out;

    // ws layout: [0..64) invnorms (floats), [64..64+25216) bits (ints),
    //            [64+25216 .. 64+2*25216) dist (floats)
    float* invn   = (float*)d_ws;
    int*   bitsws = (int*)d_ws + 64;
    float* distws = (float*)d_ws + 64 + NALLTOK;

    knorm_kernel<<<40, 64, 0, stream>>>(kc, ki, layer, invn);
    route_kernel<<<98 + BB, 256, 0, stream>>>(x, kc, ki, layer, invn, bitsws, distws);
    write_kernel<<<NALLTOK + 1, 256, 0, stream>>>(bitsws, distws, out);
}

// Round 3
// 239.820 us; speedup vs baseline: 1.4984x; 1.4984x over previous
//
#include <hip/hip_runtime.h>

// Geometry (fixed by reference)
#define NTOK 197
#define NHEADS 12
#define DIM 768
#define PP 20
#define KK 5
#define STOT 397
#define BB 128
#define NIMG 196
#define NIMGBLK 392              // 392*64 = 25088 image tokens
#define NBLK 394                 // + 2 cls blocks (128 cls tokens)
#define CHUNK 128
#define NCHUNK 6
#define PITCH 132                // floats; rows stay 16B-aligned (132*4 = 528 = 33*16)
#define HSTRIDE (NTOK * STOT)    // 78209

static const long long MASK_ELEMS = (long long)BB * NHEADS * NTOK * STOT; // 120129024

typedef float float4a __attribute__((ext_vector_type(4), aligned(4)));   // maybe-unaligned (out rows)
typedef float float4b __attribute__((ext_vector_type(4), aligned(16)));  // known-aligned

// ---------------- Kernel 1: inverse norms of the 40 keys at `layer` -------------
__global__ void knorm_kernel(const float* __restrict__ kc,
                             const float* __restrict__ ki,
                             const int* __restrict__ layer_p,
                             float* __restrict__ invn /*40 floats*/) {
    int layer = *layer_p;
    int kid = blockIdx.x;              // 0..39 ; 0-19 cls, 20-39 img
    const float* base = (kid < PP ? kc : ki) + (size_t)layer * PP * DIM;
    const float* kp = base + (size_t)(kid % PP) * DIM;
    int lane = threadIdx.x;            // 64 threads
    float s = 0.f;
    for (int i = lane; i < DIM; i += 64) { float v = kp[i]; s += v * v; }
    #pragma unroll
    for (int m = 1; m < 64; m <<= 1) s += __shfl_xor(s, m, 64);
    if (lane == 0) invn[kid] = 1.0f / fmaxf(sqrtf(s), 1e-12f);
}

// ---------------- Kernel 2: fused route + mask write ----------------------------
// 394 blocks x 64 threads. Blocks 0..391: 64 image tokens each (one per lane).
// Blocks 392..393: 64 cls tokens each. LDS-staged x chunks + broadcast keys.
__global__ __launch_bounds__(64) void fused_kernel(
        const float* __restrict__ x,
        const float* __restrict__ kc,
        const float* __restrict__ ki,
        const int* __restrict__ layer_p,
        const float* __restrict__ invn,
        float* __restrict__ out,
        float* __restrict__ dist_part /* [394] */) {
    const int blk = blockIdx.x;
    const int lane = threadIdx.x;      // 0..63
    const bool is_cls = (blk >= NIMGBLK);
    const int layer = *layer_p;

    __shared__ float xs[64 * PITCH];   // 33,792 B
    __shared__ float ks[PP * PITCH];   // 10,560 B
    __shared__ int rowoff[64];
    __shared__ int obase[64];
    __shared__ int bitsarr[64];

    // my token -> row offsets
    if (!is_cls) {
        int i = blk * 64 + lane;                   // 0..25087
        int b = i / NIMG;
        int t = i - b * NIMG;                      // 0..195
        rowoff[lane] = (b * NTOK + 1 + t) * DIM;
        obase[lane]  = (b * (NHEADS * NTOK) + 1 + t) * STOT;
    } else {
        int b = (blk - NIMGBLK) * 64 + lane;       // 0..127
        rowoff[lane] = (b * NTOK) * DIM;
        obase[lane]  = (b * (NHEADS * NTOK)) * STOT;
    }
    const float* kb = (is_cls ? kc : ki) + (size_t)layer * PP * DIM;
    const float* ik = invn + (is_cls ? 0 : PP);
    __syncthreads();

    float acc[PP];
    #pragma unroll
    for (int p = 0; p < PP; ++p) acc[p] = 0.f;
    float xsq = 0.f;

    for (int c = 0; c < NCHUNK; ++c) {
        // stage keys chunk: 20 rows x 32 f4, coalesced
        #pragma unroll
        for (int pass = 0; pass < 10; ++pass) {
            int idx = pass * 64 + lane;            // 0..639
            int kr = idx >> 5, f4 = idx & 31;
            float4b v = *(const float4b*)(kb + kr * DIM + c * CHUNK + f4 * 4);
            *(float4b*)&ks[kr * PITCH + f4 * 4] = v;
        }
        // stage x chunk: 64 rows x 32 f4, coalesced (512B runs per row)
        #pragma unroll 8
        for (int pass = 0; pass < 32; ++pass) {
            int idx = pass * 64 + lane;
            int r = idx >> 5, f4 = idx & 31;
            float4b v = *(const float4b*)(x + rowoff[r] + c * CHUNK + f4 * 4);
            *(float4b*)&xs[r * PITCH + f4 * 4] = v;
        }
        __syncthreads();
        // compute: lane owns token=lane; keys read as wave-uniform broadcasts
        #pragma unroll 2
        for (int q = 0; q < 32; ++q) {
            float4b xv = *(const float4b*)&xs[lane * PITCH + q * 4];
            xsq += xv.x * xv.x + xv.y * xv.y + xv.z * xv.z + xv.w * xv.w;
            #pragma unroll
            for (int p = 0; p < PP; ++p) {
                float4b kv = *(const float4b*)&ks[p * PITCH + q * 4];
                acc[p] += xv.x * kv.x + xv.y * kv.y + xv.z * kv.z + xv.w * kv.w;
            }
        }
        __syncthreads();
    }

    // sims + private top-5 (no cross-lane traffic)
    float invx = 1.0f / fmaxf(sqrtf(xsq), 1e-12f);
    float sims[PP];
    #pragma unroll
    for (int p = 0; p < PP; ++p) sims[p] = acc[p] * invx * ik[p];
    int bits = 0; float sum5 = 0.f;
    #pragma unroll
    for (int j = 0; j < KK; ++j) {
        int bi = 0; float bv = -3.0e38f;
        #pragma unroll
        for (int p = 0; p < PP; ++p) {
            bool ok = !((bits >> p) & 1) && (sims[p] > bv);
            bv = ok ? sims[p] : bv;
            bi = ok ? p : bi;
        }
        bits |= (1 << bi);
        sum5 += bv;
    }
    bitsarr[lane] = bits;
    float dist = (float)KK - sum5;
    #pragma unroll
    for (int m = 1; m < 64; m <<= 1) dist += __shfl_xor(dist, m, 64);
    if (lane == 0) dist_part[blk] = dist;
    __syncthreads();

    // ---- write phase: per token, 12 head-rows of 397 floats ----
    // Precompute tau-independent classification of my 8 columns.
    const int s0a = 4 * lane;            // 0..252
    const int s0b = 256 + 4 * lane;      // valid for lane < 35
    int pidx_a[4], pidx_b[4];
    float fix_a[4], fix_b[4];
    const int lo = is_cls ? 1 : 101;
    #pragma unroll
    for (int j = 0; j < 4; ++j) {
        int s = s0a + j;
        if (s == 0 || s > 200) { pidx_a[j] = -1; fix_a[j] = 1.f; }
        else if (s >= lo && s < lo + 100) { pidx_a[j] = (s - lo) / 5; fix_a[j] = 0.f; }
        else { pidx_a[j] = -1; fix_a[j] = 0.f; }
        s = s0b + j;
        if (s == 0 || s > 200) { pidx_b[j] = -1; fix_b[j] = 1.f; }
        else if (s >= lo && s < lo + 100) { pidx_b[j] = (s - lo) / 5; fix_b[j] = 0.f; }
        else { pidx_b[j] = -1; fix_b[j] = 0.f; }
    }

    for (int tau = 0; tau < 64; ++tau) {
        const int tb = bitsarr[tau];               // LDS broadcast
        float* dst0 = out + (size_t)obase[tau];
        float4a v0, v1;
        v0.x = pidx_a[0] < 0 ? fix_a[0] : (float)((tb >> pidx_a[0]) & 1);
        v0.y = pidx_a[1] < 0 ? fix_a[1] : (float)((tb >> pidx_a[1]) & 1);
        v0.z = pidx_a[2] < 0 ? fix_a[2] : (float)((tb >> pidx_a[2]) & 1);
        v0.w = pidx_a[3] < 0 ? fix_a[3] : (float)((tb >> pidx_a[3]) & 1);
        v1.x = pidx_b[0] < 0 ? fix_b[0] : (float)((tb >> pidx_b[0]) & 1);
        v1.y = pidx_b[1] < 0 ? fix_b[1] : (float)((tb >> pidx_b[1]) & 1);
        v1.z = pidx_b[2] < 0 ? fix_b[2] : (float)((tb >> pidx_b[2]) & 1);
        v1.w = pidx_b[3] < 0 ? fix_b[3] : (float)((tb >> pidx_b[3]) & 1);
        #pragma unroll
        for (int h = 0; h < NHEADS; ++h) {
            float* dst = dst0 + h * HSTRIDE;
            __builtin_nontemporal_store(v0, (float4a*)(dst + s0a));
            if (lane < 35) __builtin_nontemporal_store(v1, (float4a*)(dst + s0b));
            else if (lane == 35) __builtin_nontemporal_store(1.0f, dst + 396);
        }
    }
}

// ---------------- Kernel 3: tiny final dist reduce ------------------------------
__global__ void reduce_kernel(const float* __restrict__ dist_part,
                              float* __restrict__ out) {
    int lane = threadIdx.x;            // 64
    float si = 0.f, sc = 0.f;
    for (int i = lane; i < NIMGBLK; i += 64) si += dist_part[i];
    if (lane < 2) sc = dist_part[NIMGBLK + lane];
    #pragma unroll
    for (int m = 1; m < 64; m <<= 1) {
        si += __shfl_xor(si, m, 64);
        sc += __shfl_xor(sc, m, 64);
    }
    if (lane == 0)
        out[MASK_ELEMS] = sc * (1.0f / (BB * KK)) + si * (1.0f / (BB * NIMG * KK));
}

// ---------------- launcher ------------------------------------------------------
extern "C" void kernel_launch(void* const* d_in, const int* in_sizes, int n_in,
                              void* d_out, int out_size, void* d_ws, size_t ws_size,
                              hipStream_t stream) {
    const float* x  = (const float*)d_in[0];
    const float* kc = (const float*)d_in[1];
    const float* ki = (const float*)d_in[2];
    const int* layer = (const int*)d_in[3];
    float* out = (float*)d_out;

    // ws: [0..64) invnorms, [64..64+NBLK) per-block dist partials
    float* invn = (float*)d_ws;
    float* dpart = (float*)d_ws + 64;

    knorm_kernel<<<40, 64, 0, stream>>>(kc, ki, layer, invn);
    fused_kernel<<<NBLK, 64, 0, stream>>>(x, kc, ki, layer, invn, out, dpart);
    reduce_kernel<<<1, 64, 0, stream>>>(dpart, out);
}